// Round 9
// baseline (927.625 us; speedup 1.0000x reference)
//
#include <hip/hip_runtime.h>

#define L_SEQ 2048
#define BATCH 16
#define DIN   512
#define NOUT  1536                    // 3*D_OUT per direction
#define GSTRIDE 3072                  // 2 dirs * 1536, g row stride
#define MROWS (L_SEQ*BATCH)           // 32768
#define PROWS ((L_SEQ+2)*BATCH)       // 32800 padded rows
#define NTILES 48                     // 3 taps * 16 kk-steps of 32

typedef float    f32x4 __attribute__((ext_vector_type(4)));
typedef float    f32x2 __attribute__((ext_vector_type(2)));
typedef _Float16 half8 __attribute__((ext_vector_type(8)));
typedef _Float16 half2v __attribute__((ext_vector_type(2)));

static __device__ __forceinline__ float sigm(float x) { return 1.f / (1.f + __expf(-x)); }
static __device__ __forceinline__ float tanh_f(float x) {
  float ax = fabsf(x);
  float t = __expf(-2.f * ax);
  float r = (1.f - t) / (1.f + t);
  return x < 0.f ? -r : r;
}

// ---------------- prep: pad + fp16 convert of x ----------------
__global__ __launch_bounds__(256) void prep_x(const float* __restrict__ x,
                                              _Float16* __restrict__ xh) {
  int gid = blockIdx.x * 256 + threadIdx.x;       // 32800*64
  int pr = gid >> 6, seg = gid & 63;
  int l = (pr >> 4) - 1;
  half8 h = (half8)0;
  if (l >= 0 && l < L_SEQ) {
    const float* src = x + (size_t)(pr - 16) * DIN + seg * 8;
#pragma unroll
    for (int i = 0; i < 8; ++i) h[i] = (_Float16)src[i];
  }
  *(half8*)(xh + (size_t)gid * 8) = h;
}

// ---------------- prep: transpose W [k][d][e] -> wT [k][e][d], fp16 ----------------
__global__ __launch_bounds__(256) void prep_w(const float* __restrict__ Wf, const float* __restrict__ Wr,
                                              _Float16* __restrict__ wTf, _Float16* __restrict__ wTr) {
  __shared__ float tile[32][33];
  int bid = blockIdx.x;                 // 2 dirs * 3 k * 16 dtiles * 48 etiles = 4608
  int dir = bid & 1; bid >>= 1;
  int et = bid % 48; bid /= 48;
  int dt = bid % 16; int k = bid / 16;
  const float* W = dir ? Wr : Wf;
  _Float16* th = dir ? wTr : wTf;
  int tx = threadIdx.x & 31, ty = threadIdx.x >> 5;
  int d0 = dt * 32, e0 = et * 32;
  const float* Wk = W + (size_t)k * DIN * NOUT;
#pragma unroll
  for (int r = 0; r < 4; ++r)
    tile[ty + r * 8][tx] = Wk[(size_t)(d0 + ty + r * 8) * NOUT + e0 + tx];
  __syncthreads();
#pragma unroll
  for (int r = 0; r < 4; ++r) {
    int e = e0 + ty + r * 8;
    size_t o = (size_t)k * NOUT * DIN + (size_t)e * DIN + d0 + tx;
    th[o] = (_Float16)tile[tx][ty + r * 8];
  }
}

// ---------------- gates GEMM: 256x128 tile, both dirs, 2-deep pipeline ----------------
static __device__ __forceinline__ void gload16(const void* g, void* l) {
  __builtin_amdgcn_global_load_lds((const __attribute__((address_space(1))) void*)g,
                                   (__attribute__((address_space(3))) void*)l, 16, 0, 0);
}

__global__ __launch_bounds__(256, 3) void gemm_gates(   // 3 blocks/CU (LDS 48KB*3=144<=160)
    const _Float16* __restrict__ xh,        // [PROWS][512]
    const _Float16* __restrict__ wTf,       // [3][1536][512]
    const _Float16* __restrict__ wTr,       // [3][1536][512]
    const float* __restrict__ biasf,        // [3][1536]
    const float* __restrict__ biasr,        // [3][1536]
    _Float16* __restrict__ g)               // [32768][3072] fp16
{
  // LDS halfs: A [2][256][32] @0 (32KB), B [2][128][32] @16384 (16KB) = 48KB
  __shared__ _Float16 AB[24576];
  const int tid = threadIdx.x;
  const int wave = tid >> 6, lane = tid & 63;
  // L2 remap: 3072 = 8 XCD * 384; per XCD 16 mt-groups * 24 nt (nt inner -> x panel reuse)
  int bid = blockIdx.x;
  const int xcd = bid & 7, t0 = bid >> 3;
  const int mt = xcd * 16 + t0 / 24, nt = t0 % 24;
  const int dir = nt / 12, ntd = nt % 12;
  const int brow = mt * 256, bcol = ntd * 128;

  const _Float16* wTh = dir ? wTr : wTf;
  const float* bias   = dir ? biasr : biasf;

  // staging: thread covers (row_rel = c*64 + (tid>>2), slot = tid&3), source slot XOR-swizzled
  const int aw_col = ((tid & 3) ^ ((tid >> 3) & 3)) * 8;

  const _Float16* xbase = xh + (size_t)brow * DIN;
  const _Float16* wbase = wTh + (size_t)bcol * DIN;

  f32x4 acc[8][4];
#pragma unroll
  for (int i = 0; i < 8; ++i)
#pragma unroll
    for (int j = 0; j < 4; ++j) acc[i][j] = (f32x4)(0.f);

  const int wm = (wave >> 1) * 128, wn = (wave & 1) * 64;
  const int fr = lane & 15;
  const int fko = (((lane >> 4) ^ ((fr >> 1) & 3))) * 8;     // XOR-swizzled read slot

  auto stage = [&](int t, int buf) {
    int k = t >> 4, kk = (t & 15) * 32;
    const _Float16* xs = xbase + (size_t)(16 * k) * DIN + kk + aw_col;
    const _Float16* ws = wbase + (size_t)k * NOUT * DIN + kk + aw_col;
    // A: 4 rounds of 64 rows
#pragma unroll
    for (int c = 0; c < 4; ++c) {
      int row = c * 64 + (tid >> 2);
      gload16(xs + (size_t)row * DIN, AB + buf * 8192 + (c * 64 + (wave * 16)) * 32);
    }
    // B: 2 rounds of 64 rows
#pragma unroll
    for (int c = 0; c < 2; ++c) {
      int row = c * 64 + (tid >> 2);
      gload16(ws + (size_t)row * DIN, AB + 16384 + buf * 4096 + (c * 64 + (wave * 16)) * 32);
    }
  };

  stage(0, 0);
  for (int t = 0; t < NTILES; ++t) {
    int buf = t & 1;
    if (t + 1 < NTILES) {
      stage(t + 1, buf ^ 1);
      asm volatile("s_waitcnt vmcnt(6)" ::: "memory");   // tile t's 6 loads done; t+1's in flight
    } else {
      asm volatile("s_waitcnt vmcnt(0)" ::: "memory");
    }
    __builtin_amdgcn_s_barrier();
    __builtin_amdgcn_sched_barrier(0);
    const _Float16* la = AB + buf * 8192;
    const _Float16* lb = AB + 16384 + buf * 4096;
    half8 a[8], b[4];
#pragma unroll
    for (int i = 0; i < 8; ++i)
      a[i] = *(const half8*)(la + (wm + i * 16 + fr) * 32 + fko);
#pragma unroll
    for (int j = 0; j < 4; ++j)
      b[j] = *(const half8*)(lb + (wn + j * 16 + fr) * 32 + fko);
    __builtin_amdgcn_s_setprio(1);
#pragma unroll
    for (int i = 0; i < 8; ++i)
#pragma unroll
      for (int j = 0; j < 4; ++j)
        acc[i][j] = __builtin_amdgcn_mfma_f32_16x16x32_f16(a[i], b[j], acc[i][j], 0, 0, 0);
    __builtin_amdgcn_s_setprio(0);
    __builtin_amdgcn_sched_barrier(0);
    __builtin_amdgcn_s_barrier();
  }

  // epilogue: masked bias, store fp16 into [row][dir*1536 + col]
  const float* b0 = bias;
  const float* b1 = bias + NOUT;
  const float* b2 = bias + 2 * NOUT;
#pragma unroll
  for (int j = 0; j < 4; ++j) {
    int col = bcol + wn + j * 16 + fr;                 // 0..1535 within dir
    float bb0 = b0[col], bb1 = b1[col], bb2 = b2[col];
    size_t gcol = (size_t)dir * NOUT + col;
#pragma unroll
    for (int i = 0; i < 8; ++i) {
#pragma unroll
      for (int q = 0; q < 4; ++q) {
        int grow = brow + wm + i * 16 + (lane >> 4) * 4 + q;
        int l = grow >> 4;                             // BATCH == 16
        float bs = bb1 + (l > 0 ? bb0 : 0.f) + (l < L_SEQ - 1 ? bb2 : 0.f);
        g[(size_t)grow * GSTRIDE + gcol] = (_Float16)(acc[i][j][q] + bs);
      }
    }
  }
}

// ---------------- fo-pool: chunked linear scan, both dirs, 2 j/thread ----------------
__global__ __launch_bounds__(256) void pool_phase1(const _Float16* __restrict__ g,
                                                   float* __restrict__ Aarr, float* __restrict__ Bvarr) {
  int gid = blockIdx.x * 256 + threadIdx.x;       // 262144 threads, 2 j each
  int rev = gid >> 17;
  int idx = gid & 131071;
  int q = idx >> 12, sidx = idx & 4095;           // sidx: b*256 + j/2
  int b = sidx >> 8, j = (sidx & 255) * 2;
  const _Float16* gf = g + (size_t)b * GSTRIDE + (size_t)rev * NOUT + j;
  float A0 = 1.f, Bv0 = 0.f, A1 = 1.f, Bv1 = 0.f;
  int l0 = q * 64;
#pragma unroll 4
  for (int t = 0; t < 64; ++t) {
    int l = rev ? (l0 + 63 - t) : (l0 + t);
    size_t off = (size_t)l * (BATCH * GSTRIDE);
    half2v fp = *(const half2v*)(gf + off);
    half2v zp = *(const half2v*)(gf + off + 1024);
    float f0 = sigm((float)fp[0]), f1 = sigm((float)fp[1]);
    float z0 = tanh_f((float)zp[0]), z1 = tanh_f((float)zp[1]);
    Bv0 = f0 * z0 + (1.f - f0) * Bv0;  A0 *= (1.f - f0);
    Bv1 = f1 * z1 + (1.f - f1) * Bv1;  A1 *= (1.f - f1);
  }
  size_t o = (size_t)rev * 262144 + (size_t)q * 8192 + (size_t)b * 512 + j;
  *(f32x2*)(Aarr + o) = f32x2{A0, A1};
  *(f32x2*)(Bvarr + o) = f32x2{Bv0, Bv1};
}

__global__ __launch_bounds__(256) void pool_phase3(const _Float16* __restrict__ g,
                                                   const float* __restrict__ Aarr,
                                                   const float* __restrict__ Bvarr,
                                                   float* __restrict__ out,
                                                   float* __restrict__ lh, float* __restrict__ lc) {
  int gid = blockIdx.x * 256 + threadIdx.x;       // 262144 threads, 2 j each
  int rev = gid >> 17;
  int idx = gid & 131071;
  int q = idx >> 12, sidx = idx & 4095;
  int b = sidx >> 8, j = (sidx & 255) * 2;
  const _Float16* gf = g + (size_t)b * GSTRIDE + (size_t)rev * NOUT + j;
  const float* Ad = Aarr + (size_t)rev * 262144;
  const float* Bd = Bvarr + (size_t)rev * 262144;
  size_t so = (size_t)b * 512 + j;
  float c0 = 0.f, c1 = 0.f;
  if (!rev) {
    for (int s = 0; s < q; ++s) {
      size_t o = (size_t)s * 8192 + so;
      f32x2 Ap = *(const f32x2*)(Ad + o);
      f32x2 Bp = *(const f32x2*)(Bd + o);
      c0 = Ap[0] * c0 + Bp[0];
      c1 = Ap[1] * c1 + Bp[1];
    }
  } else {
    for (int s = 31; s > q; --s) {
      size_t o = (size_t)s * 8192 + so;
      f32x2 Ap = *(const f32x2*)(Ad + o);
      f32x2 Bp = *(const f32x2*)(Bd + o);
      c0 = Ap[0] * c0 + Bp[0];
      c1 = Ap[1] * c1 + Bp[1];
    }
  }
  int l0 = q * 64;
#pragma unroll 2
  for (int t = 0; t < 64; ++t) {
    int l = rev ? (l0 + 63 - t) : (l0 + t);
    size_t off = (size_t)l * (BATCH * GSTRIDE);
    half2v fp = *(const half2v*)(gf + off);
    half2v op = *(const half2v*)(gf + off + 512);
    half2v zp = *(const half2v*)(gf + off + 1024);
    float f0 = sigm((float)fp[0]), f1 = sigm((float)fp[1]);
    float o0 = sigm((float)op[0]), o1 = sigm((float)op[1]);
    float z0 = tanh_f((float)zp[0]), z1 = tanh_f((float)zp[1]);
    c0 = f0 * z0 + (1.f - f0) * c0;
    c1 = f1 * z1 + (1.f - f1) * c1;
    float h0 = c0 * o0, h1 = c1 * o1;
    *(f32x2*)(out + (size_t)(l * BATCH + b) * 1024 + rev * 512 + j) = f32x2{h0, h1};
    if (l == L_SEQ - 1) {
      *(f32x2*)(lh + b * 1024 + rev * 512 + j) = f32x2{h0, h1};
      *(f32x2*)(lc + b * 1024 + rev * 512 + j) = f32x2{c0, c1};
    }
  }
}

// ---------------- launch ----------------
extern "C" void kernel_launch(void* const* d_in, const int* in_sizes, int n_in,
                              void* d_out, int out_size, void* d_ws, size_t ws_size,
                              hipStream_t stream) {
  const float* x    = (const float*)d_in[0];
  const float* fwdW = (const float*)d_in[2];
  const float* fwdb = (const float*)d_in[3];
  const float* revW = (const float*)d_in[4];
  const float* revb = (const float*)d_in[5];

  float* out = (float*)d_out;
  float* lh  = out + (size_t)L_SEQ * BATCH * 1024;
  float* lc  = lh + BATCH * 1024;

  char* ws = (char*)d_ws;
  size_t off = 0;
  _Float16* g = (_Float16*)(ws + off);        off += (size_t)MROWS * GSTRIDE * 2; // 192 MB fp16
  _Float16* xhp = (_Float16*)(ws + off);      off += (size_t)PROWS * DIN * 2;     // 33.6 MB
  _Float16* wTf = (_Float16*)(ws + off);      off += (size_t)3 * NOUT * DIN * 2;  // 4.7 MB
  _Float16* wTr = (_Float16*)(ws + off);      off += (size_t)3 * NOUT * DIN * 2;
  float* Aarr  = (float*)(ws + off); off += (size_t)2 * 32 * 8192 * 4;
  float* Bvarr = (float*)(ws + off); off += (size_t)2 * 32 * 8192 * 4;

  prep_x<<<8200, 256, 0, stream>>>(x, xhp);
  prep_w<<<4608, 256, 0, stream>>>(fwdW, revW, wTf, wTr);

  gemm_gates<<<3072, 256, 0, stream>>>(xhp, wTf, wTr, fwdb, revb, g);
  pool_phase1<<<1024, 256, 0, stream>>>(g, Aarr, Bvarr);
  pool_phase3<<<1024, 256, 0, stream>>>(g, Aarr, Bvarr, out, lh, lc);
}

// Round 11
// 500.337 us; speedup vs baseline: 1.8540x; 1.8540x over previous
//
#include <hip/hip_runtime.h>

#define L_SEQ 2048
#define BATCH 16
#define DIN   512
#define NOUT  1536                    // 3*D_OUT per direction
#define GSTRIDE 3072                  // 2 dirs * 1536, g row stride
#define MROWS (L_SEQ*BATCH)           // 32768
#define PROWS ((L_SEQ+2)*BATCH)       // 32800 padded rows
#define NTILES 48                     // 3 taps * 16 kk-steps of 32

typedef float    f32x4 __attribute__((ext_vector_type(4)));
typedef float    f32x2 __attribute__((ext_vector_type(2)));
typedef _Float16 half8 __attribute__((ext_vector_type(8)));
typedef _Float16 half2v __attribute__((ext_vector_type(2)));

static __device__ __forceinline__ float sigm(float x) { return 1.f / (1.f + __expf(-x)); }
static __device__ __forceinline__ float tanh_f(float x) {
  float ax = fabsf(x);
  float t = __expf(-2.f * ax);
  float r = (1.f - t) / (1.f + t);
  return x < 0.f ? -r : r;
}

// ---------------- prep: pad + fp16 convert of x ----------------
__global__ __launch_bounds__(256) void prep_x(const float* __restrict__ x,
                                              _Float16* __restrict__ xh) {
  int gid = blockIdx.x * 256 + threadIdx.x;       // 32800*64
  int pr = gid >> 6, seg = gid & 63;
  int l = (pr >> 4) - 1;
  half8 h = (half8)0;
  if (l >= 0 && l < L_SEQ) {
    const float* src = x + (size_t)(pr - 16) * DIN + seg * 8;
#pragma unroll
    for (int i = 0; i < 8; ++i) h[i] = (_Float16)src[i];
  }
  *(half8*)(xh + (size_t)gid * 8) = h;
}

// ---------------- prep: transpose W [k][d][e] -> wT [k][e][d], fp16 ----------------
__global__ __launch_bounds__(256) void prep_w(const float* __restrict__ Wf, const float* __restrict__ Wr,
                                              _Float16* __restrict__ wTf, _Float16* __restrict__ wTr) {
  __shared__ float tile[32][33];
  int bid = blockIdx.x;                 // 2 dirs * 3 k * 16 dtiles * 48 etiles = 4608
  int dir = bid & 1; bid >>= 1;
  int et = bid % 48; bid /= 48;
  int dt = bid % 16; int k = bid / 16;
  const float* W = dir ? Wr : Wf;
  _Float16* th = dir ? wTr : wTf;
  int tx = threadIdx.x & 31, ty = threadIdx.x >> 5;
  int d0 = dt * 32, e0 = et * 32;
  const float* Wk = W + (size_t)k * DIN * NOUT;
#pragma unroll
  for (int r = 0; r < 4; ++r)
    tile[ty + r * 8][tx] = Wk[(size_t)(d0 + ty + r * 8) * NOUT + e0 + tx];
  __syncthreads();
#pragma unroll
  for (int r = 0; r < 4; ++r) {
    int e = e0 + ty + r * 8;
    size_t o = (size_t)k * NOUT * DIN + (size_t)e * DIN + d0 + tx;
    th[o] = (_Float16)tile[tx][ty + r * 8];
  }
}

// ---------------- gates GEMM: 256x128 tile, both dirs, 2-deep pipeline ----------------
static __device__ __forceinline__ void gload16(const void* g, void* l) {
  __builtin_amdgcn_global_load_lds((const __attribute__((address_space(1))) void*)g,
                                   (__attribute__((address_space(3))) void*)l, 16, 0, 0);
}

// NOTE: no min-waves clause. (256,3) capped unified VGPR+AGPR at ~170 and
// spilled the 128-AGPR accumulator -> 1.9 GB scratch writes (round 9).
__global__ __launch_bounds__(256) void gemm_gates(
    const _Float16* __restrict__ xh,        // [PROWS][512]
    const _Float16* __restrict__ wTf,       // [3][1536][512]
    const _Float16* __restrict__ wTr,       // [3][1536][512]
    const float* __restrict__ biasf,        // [3][1536]
    const float* __restrict__ biasr,        // [3][1536]
    _Float16* __restrict__ g)               // [32768][3072] fp16
{
  // LDS halfs: A [2][256][32] @0 (32KB), B [2][128][32] @16384 (16KB) = 48KB
  __shared__ _Float16 AB[24576];
  const int tid = threadIdx.x;
  const int wave = tid >> 6, lane = tid & 63;
  // L2 remap: 3072 = 8 XCD * 384; per XCD 16 mt-groups * 24 nt (nt inner -> x panel reuse)
  int bid = blockIdx.x;
  const int xcd = bid & 7, t0 = bid >> 3;
  const int mt = xcd * 16 + t0 / 24, nt = t0 % 24;
  const int dir = nt / 12, ntd = nt % 12;
  const int brow = mt * 256, bcol = ntd * 128;

  const _Float16* wTh = dir ? wTr : wTf;
  const float* bias   = dir ? biasr : biasf;

  // staging: thread covers (row_rel = c*64 + (tid>>2), slot = tid&3), source slot XOR-swizzled
  const int aw_col = ((tid & 3) ^ ((tid >> 3) & 3)) * 8;

  const _Float16* xbase = xh + (size_t)brow * DIN;
  const _Float16* wbase = wTh + (size_t)bcol * DIN;

  f32x4 acc[8][4];
#pragma unroll
  for (int i = 0; i < 8; ++i)
#pragma unroll
    for (int j = 0; j < 4; ++j) acc[i][j] = (f32x4)(0.f);

  const int wm = (wave >> 1) * 128, wn = (wave & 1) * 64;
  const int fr = lane & 15;
  const int fko = (((lane >> 4) ^ ((fr >> 1) & 3))) * 8;     // XOR-swizzled read slot

  auto stage = [&](int t, int buf) {
    int k = t >> 4, kk = (t & 15) * 32;
    const _Float16* xs = xbase + (size_t)(16 * k) * DIN + kk + aw_col;
    const _Float16* ws = wbase + (size_t)k * NOUT * DIN + kk + aw_col;
    // A: 4 rounds of 64 rows
#pragma unroll
    for (int c = 0; c < 4; ++c) {
      int row = c * 64 + (tid >> 2);
      gload16(xs + (size_t)row * DIN, AB + buf * 8192 + (c * 64 + (wave * 16)) * 32);
    }
    // B: 2 rounds of 64 rows
#pragma unroll
    for (int c = 0; c < 2; ++c) {
      int row = c * 64 + (tid >> 2);
      gload16(ws + (size_t)row * DIN, AB + 16384 + buf * 4096 + (c * 64 + (wave * 16)) * 32);
    }
  };

  stage(0, 0);
  for (int t = 0; t < NTILES; ++t) {
    int buf = t & 1;
    if (t + 1 < NTILES) {
      stage(t + 1, buf ^ 1);
      asm volatile("s_waitcnt vmcnt(6)" ::: "memory");   // tile t's 6 loads done; t+1's in flight
    } else {
      asm volatile("s_waitcnt vmcnt(0)" ::: "memory");
    }
    __builtin_amdgcn_s_barrier();
    __builtin_amdgcn_sched_barrier(0);
    const _Float16* la = AB + buf * 8192;
    const _Float16* lb = AB + 16384 + buf * 4096;
    half8 a[8], b[4];
#pragma unroll
    for (int i = 0; i < 8; ++i)
      a[i] = *(const half8*)(la + (wm + i * 16 + fr) * 32 + fko);
#pragma unroll
    for (int j = 0; j < 4; ++j)
      b[j] = *(const half8*)(lb + (wn + j * 16 + fr) * 32 + fko);
    __builtin_amdgcn_s_setprio(1);
#pragma unroll
    for (int i = 0; i < 8; ++i)
#pragma unroll
      for (int j = 0; j < 4; ++j)
        acc[i][j] = __builtin_amdgcn_mfma_f32_16x16x32_f16(a[i], b[j], acc[i][j], 0, 0, 0);
    __builtin_amdgcn_s_setprio(0);
    __builtin_amdgcn_sched_barrier(0);
    __builtin_amdgcn_s_barrier();
  }

  // epilogue: masked bias, store fp16 into [row][dir*1536 + col]
  const float* b0 = bias;
  const float* b1 = bias + NOUT;
  const float* b2 = bias + 2 * NOUT;
#pragma unroll
  for (int j = 0; j < 4; ++j) {
    int col = bcol + wn + j * 16 + fr;                 // 0..1535 within dir
    float bb0 = b0[col], bb1 = b1[col], bb2 = b2[col];
    size_t gcol = (size_t)dir * NOUT + col;
#pragma unroll
    for (int i = 0; i < 8; ++i) {
#pragma unroll
      for (int q = 0; q < 4; ++q) {
        int grow = brow + wm + i * 16 + (lane >> 4) * 4 + q;
        int l = grow >> 4;                             // BATCH == 16
        float bs = bb1 + (l > 0 ? bb0 : 0.f) + (l < L_SEQ - 1 ? bb2 : 0.f);
        g[(size_t)grow * GSTRIDE + gcol] = (_Float16)(acc[i][j][q] + bs);
      }
    }
  }
}

// ---------------- fo-pool: chunked linear scan, both dirs, 2 j/thread ----------------
__global__ __launch_bounds__(256) void pool_phase1(const _Float16* __restrict__ g,
                                                   float* __restrict__ Aarr, float* __restrict__ Bvarr) {
  int gid = blockIdx.x * 256 + threadIdx.x;       // 262144 threads, 2 j each
  int rev = gid >> 17;
  int idx = gid & 131071;
  int q = idx >> 12, sidx = idx & 4095;           // sidx: b*256 + j/2
  int b = sidx >> 8, j = (sidx & 255) * 2;
  const _Float16* gf = g + (size_t)b * GSTRIDE + (size_t)rev * NOUT + j;
  float A0 = 1.f, Bv0 = 0.f, A1 = 1.f, Bv1 = 0.f;
  int l0 = q * 64;
#pragma unroll 4
  for (int t = 0; t < 64; ++t) {
    int l = rev ? (l0 + 63 - t) : (l0 + t);
    size_t off = (size_t)l * (BATCH * GSTRIDE);
    half2v fp = *(const half2v*)(gf + off);
    half2v zp = *(const half2v*)(gf + off + 1024);
    float f0 = sigm((float)fp[0]), f1 = sigm((float)fp[1]);
    float z0 = tanh_f((float)zp[0]), z1 = tanh_f((float)zp[1]);
    Bv0 = f0 * z0 + (1.f - f0) * Bv0;  A0 *= (1.f - f0);
    Bv1 = f1 * z1 + (1.f - f1) * Bv1;  A1 *= (1.f - f1);
  }
  size_t o = (size_t)rev * 262144 + (size_t)q * 8192 + (size_t)b * 512 + j;
  *(f32x2*)(Aarr + o) = f32x2{A0, A1};
  *(f32x2*)(Bvarr + o) = f32x2{Bv0, Bv1};
}

__global__ __launch_bounds__(256) void pool_phase3(const _Float16* __restrict__ g,
                                                   const float* __restrict__ Aarr,
                                                   const float* __restrict__ Bvarr,
                                                   float* __restrict__ out,
                                                   float* __restrict__ lh, float* __restrict__ lc) {
  int gid = blockIdx.x * 256 + threadIdx.x;       // 262144 threads, 2 j each
  int rev = gid >> 17;
  int idx = gid & 131071;
  int q = idx >> 12, sidx = idx & 4095;
  int b = sidx >> 8, j = (sidx & 255) * 2;
  const _Float16* gf = g + (size_t)b * GSTRIDE + (size_t)rev * NOUT + j;
  const float* Ad = Aarr + (size_t)rev * 262144;
  const float* Bd = Bvarr + (size_t)rev * 262144;
  size_t so = (size_t)b * 512 + j;
  float c0 = 0.f, c1 = 0.f;
  if (!rev) {
    for (int s = 0; s < q; ++s) {
      size_t o = (size_t)s * 8192 + so;
      f32x2 Ap = *(const f32x2*)(Ad + o);
      f32x2 Bp = *(const f32x2*)(Bd + o);
      c0 = Ap[0] * c0 + Bp[0];
      c1 = Ap[1] * c1 + Bp[1];
    }
  } else {
    for (int s = 31; s > q; --s) {
      size_t o = (size_t)s * 8192 + so;
      f32x2 Ap = *(const f32x2*)(Ad + o);
      f32x2 Bp = *(const f32x2*)(Bd + o);
      c0 = Ap[0] * c0 + Bp[0];
      c1 = Ap[1] * c1 + Bp[1];
    }
  }
  int l0 = q * 64;
#pragma unroll 2
  for (int t = 0; t < 64; ++t) {
    int l = rev ? (l0 + 63 - t) : (l0 + t);
    size_t off = (size_t)l * (BATCH * GSTRIDE);
    half2v fp = *(const half2v*)(gf + off);
    half2v op = *(const half2v*)(gf + off + 512);
    half2v zp = *(const half2v*)(gf + off + 1024);
    float f0 = sigm((float)fp[0]), f1 = sigm((float)fp[1]);
    float o0 = sigm((float)op[0]), o1 = sigm((float)op[1]);
    float z0 = tanh_f((float)zp[0]), z1 = tanh_f((float)zp[1]);
    c0 = f0 * z0 + (1.f - f0) * c0;
    c1 = f1 * z1 + (1.f - f1) * c1;
    float h0 = c0 * o0, h1 = c1 * o1;
    *(f32x2*)(out + (size_t)(l * BATCH + b) * 1024 + rev * 512 + j) = f32x2{h0, h1};
    if (l == L_SEQ - 1) {
      *(f32x2*)(lh + b * 1024 + rev * 512 + j) = f32x2{h0, h1};
      *(f32x2*)(lc + b * 1024 + rev * 512 + j) = f32x2{c0, c1};
    }
  }
}

// ---------------- launch ----------------
extern "C" void kernel_launch(void* const* d_in, const int* in_sizes, int n_in,
                              void* d_out, int out_size, void* d_ws, size_t ws_size,
                              hipStream_t stream) {
  const float* x    = (const float*)d_in[0];
  const float* fwdW = (const float*)d_in[2];
  const float* fwdb = (const float*)d_in[3];
  const float* revW = (const float*)d_in[4];
  const float* revb = (const float*)d_in[5];

  float* out = (float*)d_out;
  float* lh  = out + (size_t)L_SEQ * BATCH * 1024;
  float* lc  = lh + BATCH * 1024;

  char* ws = (char*)d_ws;
  size_t off = 0;
  _Float16* g = (_Float16*)(ws + off);        off += (size_t)MROWS * GSTRIDE * 2; // 192 MB fp16
  _Float16* xhp = (_Float16*)(ws + off);      off += (size_t)PROWS * DIN * 2;     // 33.6 MB
  _Float16* wTf = (_Float16*)(ws + off);      off += (size_t)3 * NOUT * DIN * 2;  // 4.7 MB
  _Float16* wTr = (_Float16*)(ws + off);      off += (size_t)3 * NOUT * DIN * 2;
  float* Aarr  = (float*)(ws + off); off += (size_t)2 * 32 * 8192 * 4;
  float* Bvarr = (float*)(ws + off); off += (size_t)2 * 32 * 8192 * 4;

  prep_x<<<8200, 256, 0, stream>>>(x, xhp);
  prep_w<<<4608, 256, 0, stream>>>(fwdW, revW, wTf, wTr);

  gemm_gates<<<3072, 256, 0, stream>>>(xhp, wTf, wTr, fwdb, revb, g);
  pool_phase1<<<1024, 256, 0, stream>>>(g, Aarr, Bvarr);
  pool_phase3<<<1024, 256, 0, stream>>>(g, Aarr, Bvarr, out, lh, lc);
}

// Round 12
// 468.222 us; speedup vs baseline: 1.9812x; 1.0686x over previous
//
#include <hip/hip_runtime.h>

#define L_SEQ 2048
#define BATCH 16
#define DIN   512
#define NOUT  1536                    // 3*D_OUT per direction
#define GSTRIDE 3072                  // 2 dirs * 1536, g row stride
#define MROWS (L_SEQ*BATCH)           // 32768
#define PROWS ((L_SEQ+2)*BATCH)       // 32800 padded rows
#define NTILES 48                     // 3 taps * 16 kk-steps of 32

typedef float    f32x4 __attribute__((ext_vector_type(4)));
typedef float    f32x2 __attribute__((ext_vector_type(2)));
typedef _Float16 half8 __attribute__((ext_vector_type(8)));
typedef _Float16 half2v __attribute__((ext_vector_type(2)));

static __device__ __forceinline__ float sigm(float x) { return 1.f / (1.f + __expf(-x)); }
static __device__ __forceinline__ float tanh_f(float x) {
  float ax = fabsf(x);
  float t = __expf(-2.f * ax);
  float r = (1.f - t) / (1.f + t);
  return x < 0.f ? -r : r;
}

// ---------------- prep: pad + fp16 convert of x ----------------
__global__ __launch_bounds__(256) void prep_x(const float* __restrict__ x,
                                              _Float16* __restrict__ xh) {
  int gid = blockIdx.x * 256 + threadIdx.x;       // 32800*64
  int pr = gid >> 6, seg = gid & 63;
  int l = (pr >> 4) - 1;
  half8 h = (half8)0;
  if (l >= 0 && l < L_SEQ) {
    const float* src = x + (size_t)(pr - 16) * DIN + seg * 8;
#pragma unroll
    for (int i = 0; i < 8; ++i) h[i] = (_Float16)src[i];
  }
  *(half8*)(xh + (size_t)gid * 8) = h;
}

// ---------------- prep: transpose W [k][d][e] -> wT [k][e][d], fp16 ----------------
__global__ __launch_bounds__(256) void prep_w(const float* __restrict__ Wf, const float* __restrict__ Wr,
                                              _Float16* __restrict__ wTf, _Float16* __restrict__ wTr) {
  __shared__ float tile[32][33];
  int bid = blockIdx.x;                 // 2 dirs * 3 k * 16 dtiles * 48 etiles = 4608
  int dir = bid & 1; bid >>= 1;
  int et = bid % 48; bid /= 48;
  int dt = bid % 16; int k = bid / 16;
  const float* W = dir ? Wr : Wf;
  _Float16* th = dir ? wTr : wTf;
  int tx = threadIdx.x & 31, ty = threadIdx.x >> 5;
  int d0 = dt * 32, e0 = et * 32;
  const float* Wk = W + (size_t)k * DIN * NOUT;
#pragma unroll
  for (int r = 0; r < 4; ++r)
    tile[ty + r * 8][tx] = Wk[(size_t)(d0 + ty + r * 8) * NOUT + e0 + tx];
  __syncthreads();
#pragma unroll
  for (int r = 0; r < 4; ++r) {
    int e = e0 + ty + r * 8;
    size_t o = (size_t)k * NOUT * DIN + (size_t)e * DIN + d0 + tx;
    th[o] = (_Float16)tile[tx][ty + r * 8];
  }
}

// ---------------- gates GEMM: 256x128 tile, both dirs, 2-deep pipeline ----------------
static __device__ __forceinline__ void gload16(const void* g, void* l) {
  __builtin_amdgcn_global_load_lds((const __attribute__((address_space(1))) void*)g,
                                   (__attribute__((address_space(3))) void*)l, 16, 0, 0);
}

// (256,2): round-8-proven codegen — VGPR 96, VALUBusy 24%, 321 us.
// (256,3) spills the 128-AGPR acc (round 9, 1.9 GB scratch); no clause
// lets regalloc bloat to VGPR 120 / VALUBusy 58% (round 11, 355 us).
__global__ __launch_bounds__(256, 2) void gemm_gates(
    const _Float16* __restrict__ xh,        // [PROWS][512]
    const _Float16* __restrict__ wTf,       // [3][1536][512]
    const _Float16* __restrict__ wTr,       // [3][1536][512]
    const float* __restrict__ biasf,        // [3][1536]
    const float* __restrict__ biasr,        // [3][1536]
    _Float16* __restrict__ g)               // [32768][3072] fp16
{
  // LDS halfs: A [2][256][32] @0 (32KB), B [2][128][32] @16384 (16KB) = 48KB
  __shared__ _Float16 AB[24576];
  const int tid = threadIdx.x;
  const int wave = tid >> 6, lane = tid & 63;
  // L2 remap: 3072 = 8 XCD * 384; per XCD 16 mt-groups * 24 nt (nt inner -> x panel reuse)
  int bid = blockIdx.x;
  const int xcd = bid & 7, t0 = bid >> 3;
  const int mt = xcd * 16 + t0 / 24, nt = t0 % 24;
  const int dir = nt / 12, ntd = nt % 12;
  const int brow = mt * 256, bcol = ntd * 128;

  const _Float16* wTh = dir ? wTr : wTf;
  const float* bias   = dir ? biasr : biasf;

  // staging: thread covers (row_rel = c*64 + (tid>>2), slot = tid&3), source slot XOR-swizzled
  const int aw_col = ((tid & 3) ^ ((tid >> 3) & 3)) * 8;

  const _Float16* xbase = xh + (size_t)brow * DIN;
  const _Float16* wbase = wTh + (size_t)bcol * DIN;

  f32x4 acc[8][4];
#pragma unroll
  for (int i = 0; i < 8; ++i)
#pragma unroll
    for (int j = 0; j < 4; ++j) acc[i][j] = (f32x4)(0.f);

  const int wm = (wave >> 1) * 128, wn = (wave & 1) * 64;
  const int fr = lane & 15;
  const int fko = (((lane >> 4) ^ ((fr >> 1) & 3))) * 8;     // XOR-swizzled read slot

  auto stage = [&](int t, int buf) {
    int k = t >> 4, kk = (t & 15) * 32;
    const _Float16* xs = xbase + (size_t)(16 * k) * DIN + kk + aw_col;
    const _Float16* ws = wbase + (size_t)k * NOUT * DIN + kk + aw_col;
    // A: 4 rounds of 64 rows
#pragma unroll
    for (int c = 0; c < 4; ++c) {
      int row = c * 64 + (tid >> 2);
      gload16(xs + (size_t)row * DIN, AB + buf * 8192 + (c * 64 + (wave * 16)) * 32);
    }
    // B: 2 rounds of 64 rows
#pragma unroll
    for (int c = 0; c < 2; ++c) {
      int row = c * 64 + (tid >> 2);
      gload16(ws + (size_t)row * DIN, AB + 16384 + buf * 4096 + (c * 64 + (wave * 16)) * 32);
    }
  };

  stage(0, 0);
  for (int t = 0; t < NTILES; ++t) {
    int buf = t & 1;
    if (t + 1 < NTILES) {
      stage(t + 1, buf ^ 1);
      asm volatile("s_waitcnt vmcnt(6)" ::: "memory");   // tile t's 6 loads done; t+1's in flight
    } else {
      asm volatile("s_waitcnt vmcnt(0)" ::: "memory");
    }
    __builtin_amdgcn_s_barrier();
    __builtin_amdgcn_sched_barrier(0);
    const _Float16* la = AB + buf * 8192;
    const _Float16* lb = AB + 16384 + buf * 4096;
    half8 a[8], b[4];
#pragma unroll
    for (int i = 0; i < 8; ++i)
      a[i] = *(const half8*)(la + (wm + i * 16 + fr) * 32 + fko);
#pragma unroll
    for (int j = 0; j < 4; ++j)
      b[j] = *(const half8*)(lb + (wn + j * 16 + fr) * 32 + fko);
    __builtin_amdgcn_s_setprio(1);
#pragma unroll
    for (int i = 0; i < 8; ++i)
#pragma unroll
      for (int j = 0; j < 4; ++j)
        acc[i][j] = __builtin_amdgcn_mfma_f32_16x16x32_f16(a[i], b[j], acc[i][j], 0, 0, 0);
    __builtin_amdgcn_s_setprio(0);
    __builtin_amdgcn_sched_barrier(0);
    __builtin_amdgcn_s_barrier();
  }

  // epilogue: masked bias, store fp16 into [row][dir*1536 + col]
  const float* b0 = bias;
  const float* b1 = bias + NOUT;
  const float* b2 = bias + 2 * NOUT;
#pragma unroll
  for (int j = 0; j < 4; ++j) {
    int col = bcol + wn + j * 16 + fr;                 // 0..1535 within dir
    float bb0 = b0[col], bb1 = b1[col], bb2 = b2[col];
    size_t gcol = (size_t)dir * NOUT + col;
#pragma unroll
    for (int i = 0; i < 8; ++i) {
#pragma unroll
      for (int q = 0; q < 4; ++q) {
        int grow = brow + wm + i * 16 + (lane >> 4) * 4 + q;
        int l = grow >> 4;                             // BATCH == 16
        float bs = bb1 + (l > 0 ? bb0 : 0.f) + (l < L_SEQ - 1 ? bb2 : 0.f);
        g[(size_t)grow * GSTRIDE + gcol] = (_Float16)(acc[i][j][q] + bs);
      }
    }
  }
}

// ---------------- fo-pool: chunked linear scan, both dirs, 2 j/thread ----------------
__global__ __launch_bounds__(256) void pool_phase1(const _Float16* __restrict__ g,
                                                   float* __restrict__ Aarr, float* __restrict__ Bvarr) {
  int gid = blockIdx.x * 256 + threadIdx.x;       // 262144 threads, 2 j each
  int rev = gid >> 17;
  int idx = gid & 131071;
  int q = idx >> 12, sidx = idx & 4095;           // sidx: b*256 + j/2
  int b = sidx >> 8, j = (sidx & 255) * 2;
  const _Float16* gf = g + (size_t)b * GSTRIDE + (size_t)rev * NOUT + j;
  float A0 = 1.f, Bv0 = 0.f, A1 = 1.f, Bv1 = 0.f;
  int l0 = q * 64;
#pragma unroll 4
  for (int t = 0; t < 64; ++t) {
    int l = rev ? (l0 + 63 - t) : (l0 + t);
    size_t off = (size_t)l * (BATCH * GSTRIDE);
    half2v fp = *(const half2v*)(gf + off);
    half2v zp = *(const half2v*)(gf + off + 1024);
    float f0 = sigm((float)fp[0]), f1 = sigm((float)fp[1]);
    float z0 = tanh_f((float)zp[0]), z1 = tanh_f((float)zp[1]);
    Bv0 = f0 * z0 + (1.f - f0) * Bv0;  A0 *= (1.f - f0);
    Bv1 = f1 * z1 + (1.f - f1) * Bv1;  A1 *= (1.f - f1);
  }
  size_t o = (size_t)rev * 262144 + (size_t)q * 8192 + (size_t)b * 512 + j;
  *(f32x2*)(Aarr + o) = f32x2{A0, A1};
  *(f32x2*)(Bvarr + o) = f32x2{Bv0, Bv1};
}

__global__ __launch_bounds__(256) void pool_phase3(const _Float16* __restrict__ g,
                                                   const float* __restrict__ Aarr,
                                                   const float* __restrict__ Bvarr,
                                                   float* __restrict__ out,
                                                   float* __restrict__ lh, float* __restrict__ lc) {
  int gid = blockIdx.x * 256 + threadIdx.x;       // 262144 threads, 2 j each
  int rev = gid >> 17;
  int idx = gid & 131071;
  int q = idx >> 12, sidx = idx & 4095;
  int b = sidx >> 8, j = (sidx & 255) * 2;
  const _Float16* gf = g + (size_t)b * GSTRIDE + (size_t)rev * NOUT + j;
  const float* Ad = Aarr + (size_t)rev * 262144;
  const float* Bd = Bvarr + (size_t)rev * 262144;
  size_t so = (size_t)b * 512 + j;
  float c0 = 0.f, c1 = 0.f;
  if (!rev) {
    for (int s = 0; s < q; ++s) {
      size_t o = (size_t)s * 8192 + so;
      f32x2 Ap = *(const f32x2*)(Ad + o);
      f32x2 Bp = *(const f32x2*)(Bd + o);
      c0 = Ap[0] * c0 + Bp[0];
      c1 = Ap[1] * c1 + Bp[1];
    }
  } else {
    for (int s = 31; s > q; --s) {
      size_t o = (size_t)s * 8192 + so;
      f32x2 Ap = *(const f32x2*)(Ad + o);
      f32x2 Bp = *(const f32x2*)(Bd + o);
      c0 = Ap[0] * c0 + Bp[0];
      c1 = Ap[1] * c1 + Bp[1];
    }
  }
  int l0 = q * 64;
#pragma unroll 2
  for (int t = 0; t < 64; ++t) {
    int l = rev ? (l0 + 63 - t) : (l0 + t);
    size_t off = (size_t)l * (BATCH * GSTRIDE);
    half2v fp = *(const half2v*)(gf + off);
    half2v op = *(const half2v*)(gf + off + 512);
    half2v zp = *(const half2v*)(gf + off + 1024);
    float f0 = sigm((float)fp[0]), f1 = sigm((float)fp[1]);
    float o0 = sigm((float)op[0]), o1 = sigm((float)op[1]);
    float z0 = tanh_f((float)zp[0]), z1 = tanh_f((float)zp[1]);
    c0 = f0 * z0 + (1.f - f0) * c0;
    c1 = f1 * z1 + (1.f - f1) * c1;
    float h0 = c0 * o0, h1 = c1 * o1;
    *(f32x2*)(out + (size_t)(l * BATCH + b) * 1024 + rev * 512 + j) = f32x2{h0, h1};
    if (l == L_SEQ - 1) {
      *(f32x2*)(lh + b * 1024 + rev * 512 + j) = f32x2{h0, h1};
      *(f32x2*)(lc + b * 1024 + rev * 512 + j) = f32x2{c0, c1};
    }
  }
}

// ---------------- launch ----------------
extern "C" void kernel_launch(void* const* d_in, const int* in_sizes, int n_in,
                              void* d_out, int out_size, void* d_ws, size_t ws_size,
                              hipStream_t stream) {
  const float* x    = (const float*)d_in[0];
  const float* fwdW = (const float*)d_in[2];
  const float* fwdb = (const float*)d_in[3];
  const float* revW = (const float*)d_in[4];
  const float* revb = (const float*)d_in[5];

  float* out = (float*)d_out;
  float* lh  = out + (size_t)L_SEQ * BATCH * 1024;
  float* lc  = lh + BATCH * 1024;

  char* ws = (char*)d_ws;
  size_t off = 0;
  _Float16* g = (_Float16*)(ws + off);        off += (size_t)MROWS * GSTRIDE * 2; // 192 MB fp16
  _Float16* xhp = (_Float16*)(ws + off);      off += (size_t)PROWS * DIN * 2;     // 33.6 MB
  _Float16* wTf = (_Float16*)(ws + off);      off += (size_t)3 * NOUT * DIN * 2;  // 4.7 MB
  _Float16* wTr = (_Float16*)(ws + off);      off += (size_t)3 * NOUT * DIN * 2;
  float* Aarr  = (float*)(ws + off); off += (size_t)2 * 32 * 8192 * 4;
  float* Bvarr = (float*)(ws + off); off += (size_t)2 * 32 * 8192 * 4;

  prep_x<<<8200, 256, 0, stream>>>(x, xhp);
  prep_w<<<4608, 256, 0, stream>>>(fwdW, revW, wTf, wTr);

  gemm_gates<<<3072, 256, 0, stream>>>(xhp, wTf, wTr, fwdb, revb, g);
  pool_phase1<<<1024, 256, 0, stream>>>(g, Aarr, Bvarr);
  pool_phase3<<<1024, 256, 0, stream>>>(g, Aarr, Bvarr, out, lh, lc);
}